// Round 8
// baseline (420.803 us; speedup 1.0000x reference)
//
#include <hip/hip_runtime.h>
#include <cstdint>
#include <cstddef>

// Problem constants (fixed by the reference).
constexpr int kN = 50000;      // nodes  (< 65536 -> src ids fit in uint16)
constexpr int kE = 800000;     // edges
constexpr int kG = 512;        // graphs
constexpr float kNegSlope = 0.2f;
constexpr float kLog2e = 1.4426950408889634f;

typedef float f4v __attribute__((ext_vector_type(4)));
typedef _Float16 h2v __attribute__((ext_vector_type(2)));
typedef _Float16 h4v __attribute__((ext_vector_type(4)));
typedef _Float16 h8v __attribute__((ext_vector_type(8)));

#if defined(__has_builtin)
#if __has_builtin(__builtin_amdgcn_fdot2)
#define HAS_FDOT2 1
#endif
#if __has_builtin(__builtin_amdgcn_exp2f)
#define HAS_EXP2 1
#endif
#endif

__device__ inline float dot2f(h2v a, h2v b, float c) {
#ifdef HAS_FDOT2
  return __builtin_amdgcn_fdot2(a, b, c, false);
#else
  return c + (float)a.x * (float)b.x + (float)a.y * (float)b.y;
#endif
}

// R2/R3 lesson: libm exp2f's precise path costs ~+10%; raw v_exp_f32 with
// att pre-scaled by log2e is 1 instr.  |score| ~ 6, no fixup needed.
#ifdef HAS_EXP2
#define ATT_SC kLog2e
__device__ inline float fexp(float x) { return __builtin_amdgcn_exp2f(x); }
#else
#define ATT_SC 1.0f
__device__ inline float fexp(float x) { return __expf(x); }
#endif

// R1-R7 lessons pinned (do not re-try):
//  - DPP butterfly reduce: REGRESSED (VALU hazard waits on bottleneck pipe).
//  - LDS sad[] address table: REGRESSED vs register-sv + ds_bpermute.
//  - 2 sequential nodes/wave w/ register prefetch: scratch spill.
//  - 2 independent waves/WG: occupancy unchanged, net regression.
//  - exp2 builtin ~= __expf (win only vs libm exp2f); kept for the free mul.
//  - combined 32B CSR record: WIN (-16.7; one line touch per edge).
//  - cached (non-nt) csr/hout + full-record scatter + 256-thr pool: WIN
//    (-16.5; csr read 3x, hout read by next tmfma).
//  - R8: cursor-based scatter — pos[] intermediate eliminated (6.4 MB
//    traffic + a dependent random load per edge in scatter); hist is now
//    a pure counting kernel, 4 edges/thread.  Within-node edge order
//    changes; softmax sum is order-invariant (fp-rounding level only).

// CSR record: 32 B per edge.  [0,16): ea as 8 x fp16.  [16,20): src id u32.
// [20,32): pad (full record written -> no partial-line handling).
constexpr int kRec = 32;

// ---------------------------------------------------------------------------
// CSR build: count dst degrees -> block-scan -> fused top-scan+add (also
// emits cursor = row_ptr copy) -> cursor scatter (atomicAdd on cursor).
// ---------------------------------------------------------------------------
__global__ __launch_bounds__(256) void k_hist(const int* __restrict__ dst,
                                              int* __restrict__ counts, int n) {
  int i = (blockIdx.x * 256 + threadIdx.x) * 4;
  if (i + 3 < n) {
    int4 d = *(const int4*)(dst + i);
    atomicAdd(&counts[d.x], 1);
    atomicAdd(&counts[d.y], 1);
    atomicAdd(&counts[d.z], 1);
    atomicAdd(&counts[d.w], 1);
  } else {
    int e = min(i + 4, n);
    for (int q = i; q < e; ++q) atomicAdd(&counts[dst[q]], 1);
  }
}

__global__ __launch_bounds__(256) void k_scan_blk(const int* __restrict__ counts,
                                                  int* __restrict__ excl,
                                                  int* __restrict__ bsums, int n) {
  __shared__ int sh[256];
  int tid = threadIdx.x;
  int i = blockIdx.x * 256 + tid;
  int c = (i < n) ? counts[i] : 0;
  sh[tid] = c;
  __syncthreads();
  for (int off = 1; off < 256; off <<= 1) {
    int t = (tid >= off) ? sh[tid - off] : 0;
    __syncthreads();
    sh[tid] += t;
    __syncthreads();
  }
  if (i < n) excl[i] = sh[tid] - c;
  if (tid == 255) bsums[blockIdx.x] = sh[255];
}

__global__ __launch_bounds__(256) void k_scan_add(const int* __restrict__ excl,
                                                  const int* __restrict__ bsums,
                                                  int* __restrict__ row_ptr,
                                                  int* __restrict__ cursor,
                                                  int n, int nb) {
  __shared__ int sh[256];
  int tid = threadIdx.x;
  int c = (tid < nb) ? bsums[tid] : 0;
  sh[tid] = c;
  __syncthreads();
  for (int off = 1; off < 256; off <<= 1) {
    int t = (tid >= off) ? sh[tid - off] : 0;
    __syncthreads();
    sh[tid] += t;
    __syncthreads();
  }
  int top = (blockIdx.x > 0) ? sh[blockIdx.x - 1] : 0;
  int total = sh[nb - 1];
  __syncthreads();
  int i = blockIdx.x * 256 + tid;
  if (i < n) {
    int v = excl[i] + top;
    row_ptr[i] = v;
    cursor[i] = v;
  }
  if (i == n) row_ptr[n] = total;
}

__global__ void k_scatter(const int* __restrict__ src, const int* __restrict__ dst,
                          const float* __restrict__ eattr,
                          int* __restrict__ cursor,
                          char* __restrict__ csr, int n) {
  int i = blockIdx.x * blockDim.x + threadIdx.x;
  if (i >= n) return;
  int p = atomicAdd(&cursor[dst[i]], 1);   // slot claim; order-free (softmax
                                           // sum is order-invariant)
  const float4* s4 = (const float4*)eattr + (size_t)i * 2;
  float4 a = s4[0];
  float4 b = s4[1];
  h8v hv;
  hv[0] = (_Float16)a.x; hv[1] = (_Float16)a.y; hv[2] = (_Float16)a.z; hv[3] = (_Float16)a.w;
  hv[4] = (_Float16)b.x; hv[5] = (_Float16)b.y; hv[6] = (_Float16)b.z; hv[7] = (_Float16)b.w;
  char* r = csr + (size_t)p * kRec;
  uint4 tail;
  tail.x = (uint32_t)src[i]; tail.y = 0; tail.z = 0; tail.w = 0;
  *(h8v*)r = hv;               // bytes [0,16): ea — cached (read 3x later)
  *(uint4*)(r + 16) = tail;    // bytes [16,32): src + pad (full record)
}

// ---------------------------------------------------------------------------
// Fused prep: zeroes counts, builds graph-boundary table gptr, x -> fp16
// padded K=32 (vectorized: 8 cols / thread, h8v stores); weight pairs ->
// fp16 transposed Wt; We -> fp16 transposed Wet[ch][k].
// ---------------------------------------------------------------------------
__global__ __launch_bounds__(256) void k_prep(
    const float* __restrict__ x,
    const float* __restrict__ W1s, const float* __restrict__ W1d,
    const float* __restrict__ W2s, const float* __restrict__ W2d,
    const float* __restrict__ W3s, const float* __restrict__ W3d,
    const float* __restrict__ W1e, const float* __restrict__ W2e,
    const float* __restrict__ W3e,
    const int* __restrict__ batch, int* __restrict__ gptr,
    int* __restrict__ counts,
    _Float16* __restrict__ xf, _Float16* __restrict__ Wt1,
    _Float16* __restrict__ Wt2, _Float16* __restrict__ Wt3,
    _Float16* __restrict__ We1t, _Float16* __restrict__ We2t,
    _Float16* __restrict__ We3t, int n) {
  int i = blockIdx.x * 256 + threadIdx.x;
  if (i < n) {
    counts[i] = 0;
    // gptr[g] = first node of graph g (batch is sorted).  Avg loop len ~0.01.
    int b1 = batch[i];
    int b0 = (i == 0) ? -1 : batch[i - 1];
    for (int g = b0 + 1; g <= b1; ++g) gptr[g] = i;
    if (i == n - 1) {
      for (int g = b1 + 1; g <= kG; ++g) gptr[g] = n;
    }
  }
  i -= n;
  if (i < 0) return;
  int r0 = n * 4;  // xf: 4 threads/node, 8 cols each (h8v store)
  if (i < r0) {
    int node = i >> 2, j = i & 3;
    h8v v;
    if (j < 2) {
      const float4* xp = (const float4*)(x + node * 16 + j * 8);
      float4 a = xp[0], b = xp[1];
      v[0] = (_Float16)a.x; v[1] = (_Float16)a.y; v[2] = (_Float16)a.z; v[3] = (_Float16)a.w;
      v[4] = (_Float16)b.x; v[5] = (_Float16)b.y; v[6] = (_Float16)b.z; v[7] = (_Float16)b.w;
    } else {
#pragma unroll
      for (int q = 0; q < 8; ++q) v[q] = (_Float16)0.f;
    }
    *(h8v*)(xf + (size_t)node * 32 + j * 8) = v;
    return;
  }
  i -= r0;
  if (i < 256 * 32) {  // Wt1: 256 cols x K=32, IND=16, OUTD=128
    int c = i >> 5, k = i & 31;
    const float* W = (c < 128) ? W1s : W1d;
    Wt1[i] = (k < 16) ? (_Float16)W[k * 128 + (c & 127)] : (_Float16)0.f;
    return;
  }
  i -= 256 * 32;
  if (i < 256 * 128) {  // Wt2: 256 x 128, IND=128, OUTD=128
    int c = i >> 7, k = i & 127;
    const float* W = (c < 128) ? W2s : W2d;
    Wt2[i] = (_Float16)W[k * 128 + (c & 127)];
    return;
  }
  i -= 256 * 128;
  if (i < 64 * 128) {  // Wt3: 64 x 128, IND=128, OUTD=32
    int c = i >> 7, k = i & 127;
    const float* W = (c < 32) ? W3s : W3d;
    int cc = (c < 32) ? c : c - 32;
    Wt3[i] = (_Float16)W[k * 32 + cc];
    return;
  }
  i -= 64 * 128;
  if (i < 128 * 8) {  // We1t[ch][k] = W1e[k][ch]
    We1t[i] = (_Float16)W1e[(i & 7) * 128 + (i >> 3)];
    return;
  }
  i -= 128 * 8;
  if (i < 128 * 8) {  // We2t
    We2t[i] = (_Float16)W2e[(i & 7) * 128 + (i >> 3)];
    return;
  }
  i -= 128 * 8;
  if (i < 32 * 8) {   // We3t
    We3t[i] = (_Float16)W3e[(i & 7) * 32 + (i >> 3)];
  }
}

// ---------------------------------------------------------------------------
// MFMA node transform: [xs | xd] = h @ [Ws | Wd] + [bs | bd].
// ---------------------------------------------------------------------------
template <int KT, int NC2>
__global__ __launch_bounds__(256) void k_tmfma(
    const _Float16* __restrict__ hf, const _Float16* __restrict__ Wt,
    const float* __restrict__ bs, const float* __restrict__ bd,
    _Float16* __restrict__ xs_h, _Float16* __restrict__ xd_h, int n_nodes) {
  constexpr int K = KT * 32;
  constexpr int NCS = NC2 / 2;
  constexpr int D = NCS * 16;
  int lane = threadIdx.x & 63;
  int wid = threadIdx.x >> 6;
  int m = lane & 15;
  int quad = lane >> 4;
  int base = (blockIdx.x * 4 + wid) * 16;
  if (base >= n_nodes) return;
  int arow = min(base + m, n_nodes - 1);

  h8v a[KT];
#pragma unroll
  for (int t = 0; t < KT; ++t)
    a[t] = *(const h8v*)(hf + (size_t)arow * K + t * 32 + quad * 8);

  bool full = (base + 16 <= n_nodes);
#pragma unroll
  for (int c = 0; c < NC2; ++c) {
    f4v acc = {0.f, 0.f, 0.f, 0.f};
#pragma unroll
    for (int t = 0; t < KT; ++t) {
      h8v b = *(const h8v*)(Wt + (size_t)(c * 16 + m) * K + t * 32 + quad * 8);
      acc = __builtin_amdgcn_mfma_f32_16x16x32_f16(a[t], b, acc, 0, 0, 0);
    }
    float bv = (c < NCS) ? bs[c * 16 + m] : bd[(c - NCS) * 16 + m];
#pragma unroll
    for (int r = 0; r < 4; ++r) {
      int node = base + quad * 4 + r;
      if (full || node < n_nodes) {
        if (c < NCS)
          xs_h[(size_t)node * D + c * 16 + m] = (_Float16)(acc[r] + bv);
        else
          xd_h[(size_t)node * D + (c - NCS) * 16 + m] = (_Float16)(acc[r] + bv);
      }
    }
  }
}

// ---------------------------------------------------------------------------
// Fused GATv2, D=128 (H=4, C=32): verified-optimal hot loop (R5/R6/R7),
// combined 32B CSR record staging with cached loads.  NON-persistent, ONE
// WAVE PER BLOCK.  TWO edge slots (32 lanes/slot, 4 ch/lane).  Pipeline
// depth 2 with wave-uniform prefetch guard.  No-max softmax via raw
// v_exp_f32 in log2 domain.  Gather addressing via register sv + __shfl.
// ---------------------------------------------------------------------------
template <bool DO_ELU>
__global__ __launch_bounds__(64) void k_gat128(
    const int* __restrict__ row_ptr, const char* __restrict__ csr,
    const _Float16* __restrict__ xs_h, const _Float16* __restrict__ xd_h,
    const float* __restrict__ att, const float* __restrict__ bias,
    const _Float16* __restrict__ Wet, _Float16* __restrict__ hout, int n_nodes) {
  __shared__ _Float16 sea[64 * 8];
  int lane = threadIdx.x & 63;
  int node = blockIdx.x;
  if (node >= n_nodes) return;
  int slot = lane >> 5;   // 0 / 1
  int sl = lane & 31;
  int ch0 = sl * 4;       // this lane's 4 channels; head = sl>>3

  float4 at4 = *(const float4*)(att + ch0);
  float atl[4] = {at4.x * ATT_SC, at4.y * ATT_SC, at4.z * ATT_SC, at4.w * ATT_SC};
  h2v we[4][4];
#pragma unroll
  for (int c = 0; c < 4; ++c) {
    h8v wv = *(const h8v*)(Wet + (size_t)(ch0 + c) * 8);
#pragma unroll
    for (int t = 0; t < 4; ++t) {
      h2v w;
      w[0] = wv[2 * t];
      w[1] = wv[2 * t + 1];
      we[c][t] = w;
    }
  }
  float4 bv4 = *(const float4*)(bias + ch0);
  float bl[4] = {bv4.x, bv4.y, bv4.z, bv4.w};

  h4v xdh = *(const h4v*)(xd_h + (size_t)node * 128 + ch0);
  float xdl[4];
#pragma unroll
  for (int c = 0; c < 4; ++c) xdl[c] = (float)xdh[c];

  const char* xsb = (const char*)xs_h;
  uint32_t chb = (uint32_t)sl * 8u;  // byte offset of this lane's 4 fp16 ch

  float acc[4] = {0.f, 0.f, 0.f, 0.f};
  float l_run = 0.f;
  int beg = row_ptr[node], end = row_ptr[node + 1];

  for (int cbeg = beg; cbeg < end; cbeg += 64) {
    int cnt = min(end - cbeg, 64);
    int sv = 0;
    if (lane < cnt) {
      const char* r = csr + (size_t)(cbeg + lane) * kRec;
      h8v t = *(const h8v*)r;
      sv = (int)*(const uint32_t*)(r + 16);
      *(h8v*)&sea[lane * 8] = t;
    }

    auto addr = [&](int i) -> uint32_t {
      int s = __shfl(sv, i + slot, 64);  // idx <= 63 everywhere it's used
      return (uint32_t)s * 256u + chb;
    };
    auto consume = [&](int i, h4v xh) {
      int e = i + slot;                  // <= 63 by construction
      const h2v* pe = (const h2v*)&sea[e * 8];
      h2v a0 = pe[0], a1 = pe[1], a2 = pe[2], a3 = pe[3];
      float xf[4];
#pragma unroll
      for (int c = 0; c < 4; ++c) xf[c] = (float)xh[c];
      float sc = 0.f;
#pragma unroll
      for (int c = 0; c < 4; ++c) {
        float z = dot2f(a3, we[c][3],
                  dot2f(a2, we[c][2],
                  dot2f(a1, we[c][1],
                  dot2f(a0, we[c][0], xf[c] + xdl[c]))));
        z = fmaxf(z, kNegSlope * z);
        sc = fmaf(z, atl[c], sc);
      }
      // head score: reduce over the 8 lanes covering this head's 32 ch
      sc += __shfl_xor(sc, 1, 64);
      sc += __shfl_xor(sc, 2, 64);
      sc += __shfl_xor(sc, 4, 64);
      float p = (e < cnt) ? fexp(sc) : 0.f;
      l_run += p;
#pragma unroll
      for (int c = 0; c < 4; ++c) acc[c] += p * xf[c];
    };

    uint32_t oa = addr(0), ob = addr(2);
    h4v xa = *(const h4v*)(xsb + oa);
    h4v xb = *(const h4v*)(xsb + ob);
    for (int i = 0; i < cnt; i += 4) {
      bool pf = (i + 4 < cnt);           // wave-uniform: zero wasted gathers
      h4v pa, pb;
      if (pf) {
        uint32_t na = addr(i + 4), nb = addr(i + 6);
        pa = *(const h4v*)(xsb + na);
        pb = *(const h4v*)(xsb + nb);
      }
      consume(i, xa);
      consume(i + 2, xb);
      if (pf) { xa = pa; xb = pb; }
    }
  }

  // combine the two slots
  l_run += __shfl_xor(l_run, 32, 64);
#pragma unroll
  for (int c = 0; c < 4; ++c) acc[c] += __shfl_xor(acc[c], 32, 64);

  if (slot == 0) {
    float inv = (l_run > 0.f) ? (1.f / l_run) : 0.f;
    h4v ov;
#pragma unroll
    for (int c = 0; c < 4; ++c) {
      float o = acc[c] * inv + bl[c];
      if (DO_ELU) o = (o > 0.f) ? o : (__expf(o) - 1.f);
      ov[c] = (_Float16)o;
    }
    *(h4v*)(hout + (size_t)node * 128 + ch0) = ov;
  }
}

// ---------------------------------------------------------------------------
// Fused GATv2, D=32 (H=1, C=32): verified hot loop, cached combined-record
// staging.  One wave per block, EIGHT edge slots (8 lanes/slot, 4 ch/lane),
// pipeline depth 2 with wave-uniform guard.  Chunk = 32 edges.
// ---------------------------------------------------------------------------
template <bool DO_ELU>
__global__ __launch_bounds__(64) void k_gat32(
    const int* __restrict__ row_ptr, const char* __restrict__ csr,
    const _Float16* __restrict__ xs_h, const _Float16* __restrict__ xd_h,
    const float* __restrict__ att, const float* __restrict__ bias,
    const _Float16* __restrict__ Wet, _Float16* __restrict__ hout, int n_nodes) {
  __shared__ _Float16 sea[32 * 8];
  int lane = threadIdx.x & 63;
  int node = blockIdx.x;
  if (node >= n_nodes) return;
  int slot = lane >> 3;   // 0..7
  int sl = lane & 7;
  int ch0 = sl * 4;

  float4 at4 = *(const float4*)(att + ch0);
  float atl[4] = {at4.x * ATT_SC, at4.y * ATT_SC, at4.z * ATT_SC, at4.w * ATT_SC};
  h2v we[4][4];
#pragma unroll
  for (int c = 0; c < 4; ++c) {
    h8v wv = *(const h8v*)(Wet + (size_t)(ch0 + c) * 8);
#pragma unroll
    for (int t = 0; t < 4; ++t) {
      h2v w;
      w[0] = wv[2 * t];
      w[1] = wv[2 * t + 1];
      we[c][t] = w;
    }
  }
  float4 bv4 = *(const float4*)(bias + ch0);
  float bl[4] = {bv4.x, bv4.y, bv4.z, bv4.w};

  h4v xdh = *(const h4v*)(xd_h + (size_t)node * 32 + ch0);
  float xdl[4];
#pragma unroll
  for (int c = 0; c < 4; ++c) xdl[c] = (float)xdh[c];

  const char* xsb = (const char*)xs_h;
  uint32_t chb = (uint32_t)sl * 8u;

  float acc[4] = {0.f, 0.f, 0.f, 0.f};
  float l_run = 0.f;
  int beg = row_ptr[node], end = row_ptr[node + 1];

  for (int cbeg = beg; cbeg < end; cbeg += 32) {
    int cnt = min(end - cbeg, 32);
    int sv = 0;
    if (lane < cnt) {
      const char* r = csr + (size_t)(cbeg + lane) * kRec;
      h8v t = *(const h8v*)r;
      sv = (int)*(const uint32_t*)(r + 16);
      *(h8v*)&sea[lane * 8] = t;
    }

    auto addr = [&](int i) -> uint32_t {
      int idx = (i + slot) & 31;         // wrap within this chunk's 32 ids
      int s = __shfl(sv, idx, 64);
      return (uint32_t)s * 64u + chb;
    };
    auto consume = [&](int i, h4v xh) {
      int e = i + slot;                  // <= 31 by construction
      const h2v* pe = (const h2v*)&sea[e * 8];
      h2v a0 = pe[0], a1 = pe[1], a2 = pe[2], a3 = pe[3];
      float xf[4];
#pragma unroll
      for (int c = 0; c < 4; ++c) xf[c] = (float)xh[c];
      float sc = 0.f;
#pragma unroll
      for (int c = 0; c < 4; ++c) {
        float z = dot2f(a3, we[c][3],
                  dot2f(a2, we[c][2],
                  dot2f(a1, we[c][1],
                  dot2f(a0, we[c][0], xf[c] + xdl[c]))));
        z = fmaxf(z, kNegSlope * z);
        sc = fmaf(z, atl[c], sc);
      }
      // head = 32 ch = 8 lanes (this slot)
      sc += __shfl_xor(sc, 1, 64);
      sc += __shfl_xor(sc, 2, 64);
      sc += __shfl_xor(sc, 4, 64);
      float p = (e < cnt) ? fexp(sc) : 0.f;
      l_run += p;
#pragma unroll
      for (int c = 0; c < 4; ++c) acc[c] += p * xf[c];
    };

    uint32_t oa = addr(0), ob = addr(8);
    h4v xa = *(const h4v*)(xsb + oa);
    h4v xb = *(const h4v*)(xsb + ob);
    for (int i = 0; i < cnt; i += 16) {
      bool pf = (i + 16 < cnt);          // wave-uniform guard
      h4v pa, pb;
      if (pf) {
        uint32_t na = addr(i + 16), nb = addr(i + 24);
        pa = *(const h4v*)(xsb + na);
        pb = *(const h4v*)(xsb + nb);
      }
      consume(i, xa);
      consume(i + 8, xb);
      if (pf) { xa = pa; xb = pb; }
    }
  }

  // combine the 8 slots (lanes with equal sl)
#pragma unroll
  for (int off = 8; off < 64; off <<= 1) {
    l_run += __shfl_xor(l_run, off, 64);
#pragma unroll
    for (int c = 0; c < 4; ++c) acc[c] += __shfl_xor(acc[c], off, 64);
  }

  if (slot == 0) {
    float inv = (l_run > 0.f) ? (1.f / l_run) : 0.f;
    h4v ov;
#pragma unroll
    for (int c = 0; c < 4; ++c) {
      float o = acc[c] * inv + bl[c];
      if (DO_ELU) o = (o > 0.f) ? o : (__expf(o) - 1.f);
      ov[c] = (_Float16)o;
    }
    *(h4v*)(hout + (size_t)node * 32 + ch0) = ov;
  }
}

// ---------------------------------------------------------------------------
// Global mean-pool (fp16 input) + 2-layer MLP.  256 threads/block: 8 node-
// segments sum in parallel, LDS-reduced, then the 64-wide MLP.
// ---------------------------------------------------------------------------
__global__ __launch_bounds__(256) void k_pool_mlp(
    const _Float16* __restrict__ h3, const int* __restrict__ gptr,
    const float* __restrict__ Wm1, const float* __restrict__ bm1,
    const float* __restrict__ Wm2, const float* __restrict__ bm2,
    float* __restrict__ out, int n_nodes) {
  int g = blockIdx.x;
  int t = threadIdx.x;
  int lo = gptr[g];
  int hi = gptr[g + 1];
  int c = t & 31, seg = t >> 5;      // 8 segments x 32 channels
  float sum = 0.f;
  for (int i = lo + seg; i < hi; i += 8) sum += (float)h3[(size_t)i * 32 + c];
  __shared__ float psum[8][32];
  __shared__ float sh_emb[32];
  __shared__ float sh_hid[64];
  psum[seg][c] = sum;
  __syncthreads();
  if (t < 32) {
    float s = 0.f;
#pragma unroll
    for (int q = 0; q < 8; ++q) s += psum[q][t];
    float cnt = (float)(hi - lo);
    sh_emb[t] = s / fmaxf(cnt, 1.f);
  }
  __syncthreads();
  if (t < 64) {
    float hv = bm1[t];
    for (int k = 0; k < 32; ++k) hv += sh_emb[k] * Wm1[k * 64 + t];
    sh_hid[t] = fmaxf(hv, 0.f);
  }
  __syncthreads();
  if (t < 64) {
    float ov = bm2[t];
    for (int k = 0; k < 64; ++k) ov += sh_hid[k] * Wm2[k * 64 + t];
    out[(size_t)g * 64 + t] = ov;
  }
}

// ---------------------------------------------------------------------------
extern "C" void kernel_launch(void* const* d_in, const int* in_sizes, int n_in,
                              void* d_out, int out_size, void* d_ws, size_t ws_size,
                              hipStream_t stream) {
  const float* x = (const float*)d_in[0];
  const int* esrc = (const int*)d_in[1];
  const int* edst = (const int*)d_in[2];
  const float* eattr = (const float*)d_in[3];
  const int* batch = (const int*)d_in[4];
  const float* W1s = (const float*)d_in[5];
  const float* W1d = (const float*)d_in[6];
  const float* W1e = (const float*)d_in[7];
  const float* b1s = (const float*)d_in[8];
  const float* b1d = (const float*)d_in[9];
  const float* att1 = (const float*)d_in[10];
  const float* bias1 = (const float*)d_in[11];
  const float* W2s = (const float*)d_in[12];
  const float* W2d = (const float*)d_in[13];
  const float* W2e = (const float*)d_in[14];
  const float* b2s = (const float*)d_in[15];
  const float* b2d = (const float*)d_in[16];
  const float* att2 = (const float*)d_in[17];
  const float* bias2 = (const float*)d_in[18];
  const float* W3s = (const float*)d_in[19];
  const float* W3d = (const float*)d_in[20];
  const float* W3e = (const float*)d_in[21];
  const float* b3s = (const float*)d_in[22];
  const float* b3d = (const float*)d_in[23];
  const float* att3 = (const float*)d_in[24];
  const float* bias3 = (const float*)d_in[25];
  const float* Wm1 = (const float*)d_in[26];
  const float* bm1 = (const float*)d_in[27];
  const float* Wm2 = (const float*)d_in[28];
  const float* bm2 = (const float*)d_in[29];

  constexpr int kNB = (kN + 255) / 256;

  char* p = (char*)d_ws;
  auto take = [&](size_t bytes) {
    char* r = p;
    p += (bytes + 255) & ~(size_t)255;
    return r;
  };
  int* row_ptr = (int*)take((size_t)(kN + 1) * sizeof(int));
  int* counts = (int*)take((size_t)kN * sizeof(int));
  int* cursor = (int*)take((size_t)kN * sizeof(int));
  int* excl = (int*)take((size_t)kN * sizeof(int));
  int* bsums = (int*)take((size_t)kNB * sizeof(int));
  int* gptr = (int*)take((size_t)(kG + 1) * sizeof(int));
  char* csr = take((size_t)kE * kRec);
  _Float16* xf = (_Float16*)take((size_t)kN * 32 * sizeof(_Float16));
  _Float16* Wt1 = (_Float16*)take((size_t)256 * 32 * sizeof(_Float16));
  _Float16* Wt2 = (_Float16*)take((size_t)256 * 128 * sizeof(_Float16));
  _Float16* Wt3 = (_Float16*)take((size_t)64 * 128 * sizeof(_Float16));
  _Float16* We1t = (_Float16*)take((size_t)128 * 8 * sizeof(_Float16));
  _Float16* We2t = (_Float16*)take((size_t)128 * 8 * sizeof(_Float16));
  _Float16* We3t = (_Float16*)take((size_t)32 * 8 * sizeof(_Float16));
  _Float16* xs_h = (_Float16*)take((size_t)kN * 128 * sizeof(_Float16));
  _Float16* xd_h = (_Float16*)take((size_t)kN * 128 * sizeof(_Float16));
  _Float16* hA = (_Float16*)take((size_t)kN * 128 * sizeof(_Float16));
  _Float16* hB = (_Float16*)take((size_t)kN * 128 * sizeof(_Float16));
  _Float16* h3 = (_Float16*)take((size_t)kN * 32 * sizeof(_Float16));

  // Prep first (also zeroes counts + builds gptr) -> CSR build -> layers.
  {
    int prep_total = kN + kN * 4 + 256 * 32 + 256 * 128 + 64 * 128 +
                     128 * 8 + 128 * 8 + 32 * 8;
    k_prep<<<(prep_total + 255) / 256, 256, 0, stream>>>(
        x, W1s, W1d, W2s, W2d, W3s, W3d, W1e, W2e, W3e,
        batch, gptr, counts, xf, Wt1, Wt2, Wt3, We1t, We2t, We3t, kN);
  }
  k_hist<<<(kE / 4 + 255) / 256, 256, 0, stream>>>(edst, counts, kE);
  k_scan_blk<<<kNB, 256, 0, stream>>>(counts, excl, bsums, kN);
  k_scan_add<<<(kN + 1 + 255) / 256, 256, 0, stream>>>(excl, bsums, row_ptr,
                                                       cursor, kN, kNB);
  k_scatter<<<(kE + 255) / 256, 256, 0, stream>>>(esrc, edst, eattr, cursor,
                                                  csr, kE);

  constexpr int kTB = (kN + 63) / 64;   // transform blocks (64 nodes each)

  // Layer 1: in=16(pad 32) -> D=128, ELU
  k_tmfma<1, 16><<<kTB, 256, 0, stream>>>(xf, Wt1, b1s, b1d, xs_h, xd_h, kN);
  k_gat128<true><<<kN, 64, 0, stream>>>(row_ptr, csr, xs_h, xd_h,
                                        att1, bias1, We1t, hA, kN);
  // Layer 2: in=128 -> D=128, ELU
  k_tmfma<4, 16><<<kTB, 256, 0, stream>>>(hA, Wt2, b2s, b2d, xs_h, xd_h, kN);
  k_gat128<true><<<kN, 64, 0, stream>>>(row_ptr, csr, xs_h, xd_h,
                                        att2, bias2, We2t, hB, kN);
  // Layer 3: in=128 -> D=32, no ELU
  k_tmfma<4, 4><<<kTB, 256, 0, stream>>>(hB, Wt3, b3s, b3d, xs_h, xd_h, kN);
  k_gat32<false><<<kN, 64, 0, stream>>>(row_ptr, csr, xs_h, xd_h,
                                        att3, bias3, We3t, h3, kN);
  // Pool + MLP
  k_pool_mlp<<<kG, 256, 0, stream>>>(h3, gptr, Wm1, bm1, Wm2, bm2, (float*)d_out, kN);
}

// Round 9
// 385.512 us; speedup vs baseline: 1.0915x; 1.0915x over previous
//
#include <hip/hip_runtime.h>
#include <cstdint>
#include <cstddef>

// Problem constants (fixed by the reference).
constexpr int kN = 50000;      // nodes  (< 65536 -> src ids fit in uint16)
constexpr int kE = 800000;     // edges
constexpr int kG = 512;        // graphs
constexpr float kNegSlope = 0.2f;
constexpr float kLog2e = 1.4426950408889634f;

typedef float f4v __attribute__((ext_vector_type(4)));
typedef _Float16 h2v __attribute__((ext_vector_type(2)));
typedef _Float16 h4v __attribute__((ext_vector_type(4)));
typedef _Float16 h8v __attribute__((ext_vector_type(8)));

#if defined(__has_builtin)
#if __has_builtin(__builtin_amdgcn_fdot2)
#define HAS_FDOT2 1
#endif
#if __has_builtin(__builtin_amdgcn_exp2f)
#define HAS_EXP2 1
#endif
#endif

__device__ inline float dot2f(h2v a, h2v b, float c) {
#ifdef HAS_FDOT2
  return __builtin_amdgcn_fdot2(a, b, c, false);
#else
  return c + (float)a.x * (float)b.x + (float)a.y * (float)b.y;
#endif
}

// R2/R3 lesson: libm exp2f's precise path costs ~+10%; raw v_exp_f32 with
// att pre-scaled by log2e is 1 instr.  |score| ~ 6, no fixup needed.
#ifdef HAS_EXP2
#define ATT_SC kLog2e
__device__ inline float fexp(float x) { return __builtin_amdgcn_exp2f(x); }
#else
#define ATT_SC 1.0f
__device__ inline float fexp(float x) { return __expf(x); }
#endif

// R1-R8 lessons pinned (do not re-try):
//  - DPP butterfly reduce: REGRESSED (VALU hazard waits on bottleneck pipe).
//  - LDS sad[] address table: REGRESSED vs register-sv + ds_bpermute.
//  - 2 sequential nodes/wave w/ register prefetch: scratch spill.
//  - 2 independent waves/WG: occupancy unchanged, net regression.
//  - exp2 builtin ~= __expf (win only vs libm exp2f); kept for the free mul.
//  - combined 32B CSR record: WIN (-16.7; one line touch per edge).
//  - cached (non-nt) csr/hout + full-record scatter + 256-thr pool: WIN.
//  - R8 cursor scatter: REGRESSED +26 — atomic round-trip on scatter's
//    address critical path replaced an L2-HIT row_ptr read (row_ptr is
//    200KB, cache-resident) + linear pos read.  pos-based flow restored.
//  - R8 counters: scatter is MLP/latency-bound (VALUBusy 0.8%, WRITE 59MB
//    = partial-line RFO on random 32B records).  R9: ILP-batch hist (4
//    edges/thread) and scatter (2 edges/thread, loads hoisted).

// CSR record: 32 B per edge.  [0,16): ea as 8 x fp16.  [16,20): src id u32.
// [20,32): pad (full record written -> no partial-line handling).
constexpr int kRec = 32;

// ---------------------------------------------------------------------------
// CSR build: histogram of dst (records each edge's within-node slot in pos)
// -> block-scan -> fused top-scan+add -> scatter (no atomics in scatter).
// ---------------------------------------------------------------------------
__global__ __launch_bounds__(256) void k_hist(const int* __restrict__ dst,
                                              int* __restrict__ counts,
                                              int* __restrict__ pos, int n) {
  int i = (blockIdx.x * 256 + threadIdx.x) * 4;
  if (i + 3 < n) {
    int4 d = *(const int4*)(dst + i);
    int4 p;                      // 4 independent atomic chains in flight
    p.x = atomicAdd(&counts[d.x], 1);
    p.y = atomicAdd(&counts[d.y], 1);
    p.z = atomicAdd(&counts[d.z], 1);
    p.w = atomicAdd(&counts[d.w], 1);
    *(int4*)(pos + i) = p;
  } else {
    int e = min(i + 4, n);
    for (int q = i; q < e; ++q) pos[q] = atomicAdd(&counts[dst[q]], 1);
  }
}

__global__ __launch_bounds__(256) void k_scan_blk(const int* __restrict__ counts,
                                                  int* __restrict__ excl,
                                                  int* __restrict__ bsums, int n) {
  __shared__ int sh[256];
  int tid = threadIdx.x;
  int i = blockIdx.x * 256 + tid;
  int c = (i < n) ? counts[i] : 0;
  sh[tid] = c;
  __syncthreads();
  for (int off = 1; off < 256; off <<= 1) {
    int t = (tid >= off) ? sh[tid - off] : 0;
    __syncthreads();
    sh[tid] += t;
    __syncthreads();
  }
  if (i < n) excl[i] = sh[tid] - c;
  if (tid == 255) bsums[blockIdx.x] = sh[255];
}

__global__ __launch_bounds__(256) void k_scan_add(const int* __restrict__ excl,
                                                  const int* __restrict__ bsums,
                                                  int* __restrict__ row_ptr,
                                                  int n, int nb) {
  __shared__ int sh[256];
  int tid = threadIdx.x;
  int c = (tid < nb) ? bsums[tid] : 0;
  sh[tid] = c;
  __syncthreads();
  for (int off = 1; off < 256; off <<= 1) {
    int t = (tid >= off) ? sh[tid - off] : 0;
    __syncthreads();
    sh[tid] += t;
    __syncthreads();
  }
  int top = (blockIdx.x > 0) ? sh[blockIdx.x - 1] : 0;
  int total = sh[nb - 1];
  __syncthreads();
  int i = blockIdx.x * 256 + tid;
  if (i < n) row_ptr[i] = excl[i] + top;
  if (i == n) row_ptr[n] = total;
}

// 2 edges/thread, ALL loads issued before any dependent use: doubles
// outstanding misses per wave on a miss-queue-limited kernel (R8: VALU 0.8%).
__global__ __launch_bounds__(256) void k_scatter(
    const int* __restrict__ src, const int* __restrict__ dst,
    const float* __restrict__ eattr,
    const int* __restrict__ row_ptr, const int* __restrict__ pos,
    char* __restrict__ csr, int n) {
  int i = (blockIdx.x * 256 + threadIdx.x) * 2;
  if (i >= n) return;
  bool two = (i + 1 < n);
  int i1 = two ? i + 1 : i;
  // Issue everything up front (independent streams + 2 L2-hit gathers).
  int d0 = dst[i], d1 = dst[i1];
  int p0 = pos[i], p1 = pos[i1];
  int s0 = src[i], s1 = src[i1];
  const float4* e4 = (const float4*)eattr + (size_t)i * 2;
  float4 a0 = e4[0], b0 = e4[1];
  float4 a1 = e4[2 * (i1 - i)], b1 = e4[2 * (i1 - i) + 1];
  int q0 = row_ptr[d0] + p0;
  int q1 = row_ptr[d1] + p1;

  h8v hv0;
  hv0[0] = (_Float16)a0.x; hv0[1] = (_Float16)a0.y; hv0[2] = (_Float16)a0.z; hv0[3] = (_Float16)a0.w;
  hv0[4] = (_Float16)b0.x; hv0[5] = (_Float16)b0.y; hv0[6] = (_Float16)b0.z; hv0[7] = (_Float16)b0.w;
  uint4 t0;
  t0.x = (uint32_t)s0; t0.y = 0; t0.z = 0; t0.w = 0;
  char* r0 = csr + (size_t)q0 * kRec;
  *(h8v*)r0 = hv0;
  *(uint4*)(r0 + 16) = t0;

  if (two) {
    h8v hv1;
    hv1[0] = (_Float16)a1.x; hv1[1] = (_Float16)a1.y; hv1[2] = (_Float16)a1.z; hv1[3] = (_Float16)a1.w;
    hv1[4] = (_Float16)b1.x; hv1[5] = (_Float16)b1.y; hv1[6] = (_Float16)b1.z; hv1[7] = (_Float16)b1.w;
    uint4 t1;
    t1.x = (uint32_t)s1; t1.y = 0; t1.z = 0; t1.w = 0;
    char* r1 = csr + (size_t)q1 * kRec;
    *(h8v*)r1 = hv1;
    *(uint4*)(r1 + 16) = t1;
  }
}

// ---------------------------------------------------------------------------
// Fused prep: zeroes counts, builds graph-boundary table gptr, x -> fp16
// padded K=32 (vectorized: 8 cols / thread, h8v stores); weight pairs ->
// fp16 transposed Wt; We -> fp16 transposed Wet[ch][k].
// ---------------------------------------------------------------------------
__global__ __launch_bounds__(256) void k_prep(
    const float* __restrict__ x,
    const float* __restrict__ W1s, const float* __restrict__ W1d,
    const float* __restrict__ W2s, const float* __restrict__ W2d,
    const float* __restrict__ W3s, const float* __restrict__ W3d,
    const float* __restrict__ W1e, const float* __restrict__ W2e,
    const float* __restrict__ W3e,
    const int* __restrict__ batch, int* __restrict__ gptr,
    int* __restrict__ counts,
    _Float16* __restrict__ xf, _Float16* __restrict__ Wt1,
    _Float16* __restrict__ Wt2, _Float16* __restrict__ Wt3,
    _Float16* __restrict__ We1t, _Float16* __restrict__ We2t,
    _Float16* __restrict__ We3t, int n) {
  int i = blockIdx.x * 256 + threadIdx.x;
  if (i < n) {
    counts[i] = 0;
    // gptr[g] = first node of graph g (batch is sorted).  Avg loop len ~0.01.
    int b1 = batch[i];
    int b0 = (i == 0) ? -1 : batch[i - 1];
    for (int g = b0 + 1; g <= b1; ++g) gptr[g] = i;
    if (i == n - 1) {
      for (int g = b1 + 1; g <= kG; ++g) gptr[g] = n;
    }
  }
  i -= n;
  if (i < 0) return;
  int r0 = n * 4;  // xf: 4 threads/node, 8 cols each (h8v store)
  if (i < r0) {
    int node = i >> 2, j = i & 3;
    h8v v;
    if (j < 2) {
      const float4* xp = (const float4*)(x + node * 16 + j * 8);
      float4 a = xp[0], b = xp[1];
      v[0] = (_Float16)a.x; v[1] = (_Float16)a.y; v[2] = (_Float16)a.z; v[3] = (_Float16)a.w;
      v[4] = (_Float16)b.x; v[5] = (_Float16)b.y; v[6] = (_Float16)b.z; v[7] = (_Float16)b.w;
    } else {
#pragma unroll
      for (int q = 0; q < 8; ++q) v[q] = (_Float16)0.f;
    }
    *(h8v*)(xf + (size_t)node * 32 + j * 8) = v;
    return;
  }
  i -= r0;
  if (i < 256 * 32) {  // Wt1: 256 cols x K=32, IND=16, OUTD=128
    int c = i >> 5, k = i & 31;
    const float* W = (c < 128) ? W1s : W1d;
    Wt1[i] = (k < 16) ? (_Float16)W[k * 128 + (c & 127)] : (_Float16)0.f;
    return;
  }
  i -= 256 * 32;
  if (i < 256 * 128) {  // Wt2: 256 x 128, IND=128, OUTD=128
    int c = i >> 7, k = i & 127;
    const float* W = (c < 128) ? W2s : W2d;
    Wt2[i] = (_Float16)W[k * 128 + (c & 127)];
    return;
  }
  i -= 256 * 128;
  if (i < 64 * 128) {  // Wt3: 64 x 128, IND=128, OUTD=32
    int c = i >> 7, k = i & 127;
    const float* W = (c < 32) ? W3s : W3d;
    int cc = (c < 32) ? c : c - 32;
    Wt3[i] = (_Float16)W[k * 32 + cc];
    return;
  }
  i -= 64 * 128;
  if (i < 128 * 8) {  // We1t[ch][k] = W1e[k][ch]
    We1t[i] = (_Float16)W1e[(i & 7) * 128 + (i >> 3)];
    return;
  }
  i -= 128 * 8;
  if (i < 128 * 8) {  // We2t
    We2t[i] = (_Float16)W2e[(i & 7) * 128 + (i >> 3)];
    return;
  }
  i -= 128 * 8;
  if (i < 32 * 8) {   // We3t
    We3t[i] = (_Float16)W3e[(i & 7) * 32 + (i >> 3)];
  }
}

// ---------------------------------------------------------------------------
// MFMA node transform: [xs | xd] = h @ [Ws | Wd] + [bs | bd].
// ---------------------------------------------------------------------------
template <int KT, int NC2>
__global__ __launch_bounds__(256) void k_tmfma(
    const _Float16* __restrict__ hf, const _Float16* __restrict__ Wt,
    const float* __restrict__ bs, const float* __restrict__ bd,
    _Float16* __restrict__ xs_h, _Float16* __restrict__ xd_h, int n_nodes) {
  constexpr int K = KT * 32;
  constexpr int NCS = NC2 / 2;
  constexpr int D = NCS * 16;
  int lane = threadIdx.x & 63;
  int wid = threadIdx.x >> 6;
  int m = lane & 15;
  int quad = lane >> 4;
  int base = (blockIdx.x * 4 + wid) * 16;
  if (base >= n_nodes) return;
  int arow = min(base + m, n_nodes - 1);

  h8v a[KT];
#pragma unroll
  for (int t = 0; t < KT; ++t)
    a[t] = *(const h8v*)(hf + (size_t)arow * K + t * 32 + quad * 8);

  bool full = (base + 16 <= n_nodes);
#pragma unroll
  for (int c = 0; c < NC2; ++c) {
    f4v acc = {0.f, 0.f, 0.f, 0.f};
#pragma unroll
    for (int t = 0; t < KT; ++t) {
      h8v b = *(const h8v*)(Wt + (size_t)(c * 16 + m) * K + t * 32 + quad * 8);
      acc = __builtin_amdgcn_mfma_f32_16x16x32_f16(a[t], b, acc, 0, 0, 0);
    }
    float bv = (c < NCS) ? bs[c * 16 + m] : bd[(c - NCS) * 16 + m];
#pragma unroll
    for (int r = 0; r < 4; ++r) {
      int node = base + quad * 4 + r;
      if (full || node < n_nodes) {
        if (c < NCS)
          xs_h[(size_t)node * D + c * 16 + m] = (_Float16)(acc[r] + bv);
        else
          xd_h[(size_t)node * D + (c - NCS) * 16 + m] = (_Float16)(acc[r] + bv);
      }
    }
  }
}

// ---------------------------------------------------------------------------
// Fused GATv2, D=128 (H=4, C=32): verified-optimal hot loop (R5/R6/R7),
// combined 32B CSR record staging with cached loads.  NON-persistent, ONE
// WAVE PER BLOCK.  TWO edge slots (32 lanes/slot, 4 ch/lane).  Pipeline
// depth 2 with wave-uniform prefetch guard.  No-max softmax via raw
// v_exp_f32 in log2 domain.  Gather addressing via register sv + __shfl.
// ---------------------------------------------------------------------------
template <bool DO_ELU>
__global__ __launch_bounds__(64) void k_gat128(
    const int* __restrict__ row_ptr, const char* __restrict__ csr,
    const _Float16* __restrict__ xs_h, const _Float16* __restrict__ xd_h,
    const float* __restrict__ att, const float* __restrict__ bias,
    const _Float16* __restrict__ Wet, _Float16* __restrict__ hout, int n_nodes) {
  __shared__ _Float16 sea[64 * 8];
  int lane = threadIdx.x & 63;
  int node = blockIdx.x;
  if (node >= n_nodes) return;
  int slot = lane >> 5;   // 0 / 1
  int sl = lane & 31;
  int ch0 = sl * 4;       // this lane's 4 channels; head = sl>>3

  float4 at4 = *(const float4*)(att + ch0);
  float atl[4] = {at4.x * ATT_SC, at4.y * ATT_SC, at4.z * ATT_SC, at4.w * ATT_SC};
  h2v we[4][4];
#pragma unroll
  for (int c = 0; c < 4; ++c) {
    h8v wv = *(const h8v*)(Wet + (size_t)(ch0 + c) * 8);
#pragma unroll
    for (int t = 0; t < 4; ++t) {
      h2v w;
      w[0] = wv[2 * t];
      w[1] = wv[2 * t + 1];
      we[c][t] = w;
    }
  }
  float4 bv4 = *(const float4*)(bias + ch0);
  float bl[4] = {bv4.x, bv4.y, bv4.z, bv4.w};

  h4v xdh = *(const h4v*)(xd_h + (size_t)node * 128 + ch0);
  float xdl[4];
#pragma unroll
  for (int c = 0; c < 4; ++c) xdl[c] = (float)xdh[c];

  const char* xsb = (const char*)xs_h;
  uint32_t chb = (uint32_t)sl * 8u;  // byte offset of this lane's 4 fp16 ch

  float acc[4] = {0.f, 0.f, 0.f, 0.f};
  float l_run = 0.f;
  int beg = row_ptr[node], end = row_ptr[node + 1];

  for (int cbeg = beg; cbeg < end; cbeg += 64) {
    int cnt = min(end - cbeg, 64);
    int sv = 0;
    if (lane < cnt) {
      const char* r = csr + (size_t)(cbeg + lane) * kRec;
      h8v t = *(const h8v*)r;
      sv = (int)*(const uint32_t*)(r + 16);
      *(h8v*)&sea[lane * 8] = t;
    }

    auto addr = [&](int i) -> uint32_t {
      int s = __shfl(sv, i + slot, 64);  // idx <= 63 everywhere it's used
      return (uint32_t)s * 256u + chb;
    };
    auto consume = [&](int i, h4v xh) {
      int e = i + slot;                  // <= 63 by construction
      const h2v* pe = (const h2v*)&sea[e * 8];
      h2v a0 = pe[0], a1 = pe[1], a2 = pe[2], a3 = pe[3];
      float xf[4];
#pragma unroll
      for (int c = 0; c < 4; ++c) xf[c] = (float)xh[c];
      float sc = 0.f;
#pragma unroll
      for (int c = 0; c < 4; ++c) {
        float z = dot2f(a3, we[c][3],
                  dot2f(a2, we[c][2],
                  dot2f(a1, we[c][1],
                  dot2f(a0, we[c][0], xf[c] + xdl[c]))));
        z = fmaxf(z, kNegSlope * z);
        sc = fmaf(z, atl[c], sc);
      }
      // head score: reduce over the 8 lanes covering this head's 32 ch
      sc += __shfl_xor(sc, 1, 64);
      sc += __shfl_xor(sc, 2, 64);
      sc += __shfl_xor(sc, 4, 64);
      float p = (e < cnt) ? fexp(sc) : 0.f;
      l_run += p;
#pragma unroll
      for (int c = 0; c < 4; ++c) acc[c] += p * xf[c];
    };

    uint32_t oa = addr(0), ob = addr(2);
    h4v xa = *(const h4v*)(xsb + oa);
    h4v xb = *(const h4v*)(xsb + ob);
    for (int i = 0; i < cnt; i += 4) {
      bool pf = (i + 4 < cnt);           // wave-uniform: zero wasted gathers
      h4v pa, pb;
      if (pf) {
        uint32_t na = addr(i + 4), nb = addr(i + 6);
        pa = *(const h4v*)(xsb + na);
        pb = *(const h4v*)(xsb + nb);
      }
      consume(i, xa);
      consume(i + 2, xb);
      if (pf) { xa = pa; xb = pb; }
    }
  }

  // combine the two slots
  l_run += __shfl_xor(l_run, 32, 64);
#pragma unroll
  for (int c = 0; c < 4; ++c) acc[c] += __shfl_xor(acc[c], 32, 64);

  if (slot == 0) {
    float inv = (l_run > 0.f) ? (1.f / l_run) : 0.f;
    h4v ov;
#pragma unroll
    for (int c = 0; c < 4; ++c) {
      float o = acc[c] * inv + bl[c];
      if (DO_ELU) o = (o > 0.f) ? o : (__expf(o) - 1.f);
      ov[c] = (_Float16)o;
    }
    *(h4v*)(hout + (size_t)node * 128 + ch0) = ov;
  }
}

// ---------------------------------------------------------------------------
// Fused GATv2, D=32 (H=1, C=32): verified hot loop, cached combined-record
// staging.  One wave per block, EIGHT edge slots (8 lanes/slot, 4 ch/lane),
// pipeline depth 2 with wave-uniform guard.  Chunk = 32 edges.
// ---------------------------------------------------------------------------
template <bool DO_ELU>
__global__ __launch_bounds__(64) void k_gat32(
    const int* __restrict__ row_ptr, const char* __restrict__ csr,
    const _Float16* __restrict__ xs_h, const _Float16* __restrict__ xd_h,
    const float* __restrict__ att, const float* __restrict__ bias,
    const _Float16* __restrict__ Wet, _Float16* __restrict__ hout, int n_nodes) {
  __shared__ _Float16 sea[32 * 8];
  int lane = threadIdx.x & 63;
  int node = blockIdx.x;
  if (node >= n_nodes) return;
  int slot = lane >> 3;   // 0..7
  int sl = lane & 7;
  int ch0 = sl * 4;

  float4 at4 = *(const float4*)(att + ch0);
  float atl[4] = {at4.x * ATT_SC, at4.y * ATT_SC, at4.z * ATT_SC, at4.w * ATT_SC};
  h2v we[4][4];
#pragma unroll
  for (int c = 0; c < 4; ++c) {
    h8v wv = *(const h8v*)(Wet + (size_t)(ch0 + c) * 8);
#pragma unroll
    for (int t = 0; t < 4; ++t) {
      h2v w;
      w[0] = wv[2 * t];
      w[1] = wv[2 * t + 1];
      we[c][t] = w;
    }
  }
  float4 bv4 = *(const float4*)(bias + ch0);
  float bl[4] = {bv4.x, bv4.y, bv4.z, bv4.w};

  h4v xdh = *(const h4v*)(xd_h + (size_t)node * 32 + ch0);
  float xdl[4];
#pragma unroll
  for (int c = 0; c < 4; ++c) xdl[c] = (float)xdh[c];

  const char* xsb = (const char*)xs_h;
  uint32_t chb = (uint32_t)sl * 8u;

  float acc[4] = {0.f, 0.f, 0.f, 0.f};
  float l_run = 0.f;
  int beg = row_ptr[node], end = row_ptr[node + 1];

  for (int cbeg = beg; cbeg < end; cbeg += 32) {
    int cnt = min(end - cbeg, 32);
    int sv = 0;
    if (lane < cnt) {
      const char* r = csr + (size_t)(cbeg + lane) * kRec;
      h8v t = *(const h8v*)r;
      sv = (int)*(const uint32_t*)(r + 16);
      *(h8v*)&sea[lane * 8] = t;
    }

    auto addr = [&](int i) -> uint32_t {
      int idx = (i + slot) & 31;         // wrap within this chunk's 32 ids
      int s = __shfl(sv, idx, 64);
      return (uint32_t)s * 64u + chb;
    };
    auto consume = [&](int i, h4v xh) {
      int e = i + slot;                  // <= 31 by construction
      const h2v* pe = (const h2v*)&sea[e * 8];
      h2v a0 = pe[0], a1 = pe[1], a2 = pe[2], a3 = pe[3];
      float xf[4];
#pragma unroll
      for (int c = 0; c < 4; ++c) xf[c] = (float)xh[c];
      float sc = 0.f;
#pragma unroll
      for (int c = 0; c < 4; ++c) {
        float z = dot2f(a3, we[c][3],
                  dot2f(a2, we[c][2],
                  dot2f(a1, we[c][1],
                  dot2f(a0, we[c][0], xf[c] + xdl[c]))));
        z = fmaxf(z, kNegSlope * z);
        sc = fmaf(z, atl[c], sc);
      }
      // head = 32 ch = 8 lanes (this slot)
      sc += __shfl_xor(sc, 1, 64);
      sc += __shfl_xor(sc, 2, 64);
      sc += __shfl_xor(sc, 4, 64);
      float p = (e < cnt) ? fexp(sc) : 0.f;
      l_run += p;
#pragma unroll
      for (int c = 0; c < 4; ++c) acc[c] += p * xf[c];
    };

    uint32_t oa = addr(0), ob = addr(8);
    h4v xa = *(const h4v*)(xsb + oa);
    h4v xb = *(const h4v*)(xsb + ob);
    for (int i = 0; i < cnt; i += 16) {
      bool pf = (i + 16 < cnt);          // wave-uniform guard
      h4v pa, pb;
      if (pf) {
        uint32_t na = addr(i + 16), nb = addr(i + 24);
        pa = *(const h4v*)(xsb + na);
        pb = *(const h4v*)(xsb + nb);
      }
      consume(i, xa);
      consume(i + 8, xb);
      if (pf) { xa = pa; xb = pb; }
    }
  }

  // combine the 8 slots (lanes with equal sl)
#pragma unroll
  for (int off = 8; off < 64; off <<= 1) {
    l_run += __shfl_xor(l_run, off, 64);
#pragma unroll
    for (int c = 0; c < 4; ++c) acc[c] += __shfl_xor(acc[c], off, 64);
  }

  if (slot == 0) {
    float inv = (l_run > 0.f) ? (1.f / l_run) : 0.f;
    h4v ov;
#pragma unroll
    for (int c = 0; c < 4; ++c) {
      float o = acc[c] * inv + bl[c];
      if (DO_ELU) o = (o > 0.f) ? o : (__expf(o) - 1.f);
      ov[c] = (_Float16)o;
    }
    *(h4v*)(hout + (size_t)node * 32 + ch0) = ov;
  }
}

// ---------------------------------------------------------------------------
// Global mean-pool (fp16 input) + 2-layer MLP.  256 threads/block: 8 node-
// segments sum in parallel, LDS-reduced, then the 64-wide MLP.
// ---------------------------------------------------------------------------
__global__ __launch_bounds__(256) void k_pool_mlp(
    const _Float16* __restrict__ h3, const int* __restrict__ gptr,
    const float* __restrict__ Wm1, const float* __restrict__ bm1,
    const float* __restrict__ Wm2, const float* __restrict__ bm2,
    float* __restrict__ out, int n_nodes) {
  int g = blockIdx.x;
  int t = threadIdx.x;
  int lo = gptr[g];
  int hi = gptr[g + 1];
  int c = t & 31, seg = t >> 5;      // 8 segments x 32 channels
  float sum = 0.f;
  for (int i = lo + seg; i < hi; i += 8) sum += (float)h3[(size_t)i * 32 + c];
  __shared__ float psum[8][32];
  __shared__ float sh_emb[32];
  __shared__ float sh_hid[64];
  psum[seg][c] = sum;
  __syncthreads();
  if (t < 32) {
    float s = 0.f;
#pragma unroll
    for (int q = 0; q < 8; ++q) s += psum[q][t];
    float cnt = (float)(hi - lo);
    sh_emb[t] = s / fmaxf(cnt, 1.f);
  }
  __syncthreads();
  if (t < 64) {
    float hv = bm1[t];
    for (int k = 0; k < 32; ++k) hv += sh_emb[k] * Wm1[k * 64 + t];
    sh_hid[t] = fmaxf(hv, 0.f);
  }
  __syncthreads();
  if (t < 64) {
    float ov = bm2[t];
    for (int k = 0; k < 64; ++k) ov += sh_hid[k] * Wm2[k * 64 + t];
    out[(size_t)g * 64 + t] = ov;
  }
}

// ---------------------------------------------------------------------------
extern "C" void kernel_launch(void* const* d_in, const int* in_sizes, int n_in,
                              void* d_out, int out_size, void* d_ws, size_t ws_size,
                              hipStream_t stream) {
  const float* x = (const float*)d_in[0];
  const int* esrc = (const int*)d_in[1];
  const int* edst = (const int*)d_in[2];
  const float* eattr = (const float*)d_in[3];
  const int* batch = (const int*)d_in[4];
  const float* W1s = (const float*)d_in[5];
  const float* W1d = (const float*)d_in[6];
  const float* W1e = (const float*)d_in[7];
  const float* b1s = (const float*)d_in[8];
  const float* b1d = (const float*)d_in[9];
  const float* att1 = (const float*)d_in[10];
  const float* bias1 = (const float*)d_in[11];
  const float* W2s = (const float*)d_in[12];
  const float* W2d = (const float*)d_in[13];
  const float* W2e = (const float*)d_in[14];
  const float* b2s = (const float*)d_in[15];
  const float* b2d = (const float*)d_in[16];
  const float* att2 = (const float*)d_in[17];
  const float* bias2 = (const float*)d_in[18];
  const float* W3s = (const float*)d_in[19];
  const float* W3d = (const float*)d_in[20];
  const float* W3e = (const float*)d_in[21];
  const float* b3s = (const float*)d_in[22];
  const float* b3d = (const float*)d_in[23];
  const float* att3 = (const float*)d_in[24];
  const float* bias3 = (const float*)d_in[25];
  const float* Wm1 = (const float*)d_in[26];
  const float* bm1 = (const float*)d_in[27];
  const float* Wm2 = (const float*)d_in[28];
  const float* bm2 = (const float*)d_in[29];

  constexpr int kNB = (kN + 255) / 256;

  char* p = (char*)d_ws;
  auto take = [&](size_t bytes) {
    char* r = p;
    p += (bytes + 255) & ~(size_t)255;
    return r;
  };
  int* row_ptr = (int*)take((size_t)(kN + 1) * sizeof(int));
  int* counts = (int*)take((size_t)kN * sizeof(int));
  int* pos = (int*)take((size_t)kE * sizeof(int));
  int* excl = (int*)take((size_t)kN * sizeof(int));
  int* bsums = (int*)take((size_t)kNB * sizeof(int));
  int* gptr = (int*)take((size_t)(kG + 1) * sizeof(int));
  char* csr = take((size_t)kE * kRec);
  _Float16* xf = (_Float16*)take((size_t)kN * 32 * sizeof(_Float16));
  _Float16* Wt1 = (_Float16*)take((size_t)256 * 32 * sizeof(_Float16));
  _Float16* Wt2 = (_Float16*)take((size_t)256 * 128 * sizeof(_Float16));
  _Float16* Wt3 = (_Float16*)take((size_t)64 * 128 * sizeof(_Float16));
  _Float16* We1t = (_Float16*)take((size_t)128 * 8 * sizeof(_Float16));
  _Float16* We2t = (_Float16*)take((size_t)128 * 8 * sizeof(_Float16));
  _Float16* We3t = (_Float16*)take((size_t)32 * 8 * sizeof(_Float16));
  _Float16* xs_h = (_Float16*)take((size_t)kN * 128 * sizeof(_Float16));
  _Float16* xd_h = (_Float16*)take((size_t)kN * 128 * sizeof(_Float16));
  _Float16* hA = (_Float16*)take((size_t)kN * 128 * sizeof(_Float16));
  _Float16* hB = (_Float16*)take((size_t)kN * 128 * sizeof(_Float16));
  _Float16* h3 = (_Float16*)take((size_t)kN * 32 * sizeof(_Float16));

  // Prep first (also zeroes counts + builds gptr) -> CSR build -> layers.
  {
    int prep_total = kN + kN * 4 + 256 * 32 + 256 * 128 + 64 * 128 +
                     128 * 8 + 128 * 8 + 32 * 8;
    k_prep<<<(prep_total + 255) / 256, 256, 0, stream>>>(
        x, W1s, W1d, W2s, W2d, W3s, W3d, W1e, W2e, W3e,
        batch, gptr, counts, xf, Wt1, Wt2, Wt3, We1t, We2t, We3t, kN);
  }
  k_hist<<<(kE / 4 + 255) / 256, 256, 0, stream>>>(edst, counts, pos, kE);
  k_scan_blk<<<kNB, 256, 0, stream>>>(counts, excl, bsums, kN);
  k_scan_add<<<(kN + 1 + 255) / 256, 256, 0, stream>>>(excl, bsums, row_ptr, kN, kNB);
  k_scatter<<<(kE / 2 + 255) / 256, 256, 0, stream>>>(esrc, edst, eattr, row_ptr,
                                                      pos, csr, kE);

  constexpr int kTB = (kN + 63) / 64;   // transform blocks (64 nodes each)

  // Layer 1: in=16(pad 32) -> D=128, ELU
  k_tmfma<1, 16><<<kTB, 256, 0, stream>>>(xf, Wt1, b1s, b1d, xs_h, xd_h, kN);
  k_gat128<true><<<kN, 64, 0, stream>>>(row_ptr, csr, xs_h, xd_h,
                                        att1, bias1, We1t, hA, kN);
  // Layer 2: in=128 -> D=128, ELU
  k_tmfma<4, 16><<<kTB, 256, 0, stream>>>(hA, Wt2, b2s, b2d, xs_h, xd_h, kN);
  k_gat128<true><<<kN, 64, 0, stream>>>(row_ptr, csr, xs_h, xd_h,
                                        att2, bias2, We2t, hB, kN);
  // Layer 3: in=128 -> D=32, no ELU
  k_tmfma<4, 4><<<kTB, 256, 0, stream>>>(hB, Wt3, b3s, b3d, xs_h, xd_h, kN);
  k_gat32<false><<<kN, 64, 0, stream>>>(row_ptr, csr, xs_h, xd_h,
                                        att3, bias3, We3t, h3, kN);
  // Pool + MLP
  k_pool_mlp<<<kG, 256, 0, stream>>>(h3, gptr, Wm1, bm1, Wm2, bm2, (float*)d_out, kN);
}